// Round 7
// baseline (32.121 us; speedup 1.0000x reference)
//
#include <hip/hip_runtime.h>
#include <hip/hip_bf16.h>

#define MM 4096
#define NN 512
#define RR 32

__device__ __forceinline__ float softplus_f(float x) {
    return x > 20.0f ? x : log1pf(__expf(x));
}

// ---------------------------------------------------------------------------
// Kernel A: 32 independent 4096-point FFTs of softplus(H) rows.
// Radix-4 Stockham autosort DIF (6 stages), e^{-2pi i kn/N}. Unchanged
// (verified rounds 5-6).
// ---------------------------------------------------------------------------
__global__ __launch_bounds__(1024) void fft_rows_kernel(const float* __restrict__ H,
                                                        float2* __restrict__ hft) {
    __shared__ float2 buf[2][MM];   // 64 KB
    const int d   = blockIdx.x;
    const int tid = threadIdx.x;
    const float* Hrow = H + (size_t)d * MM;

    for (int t = tid; t < MM; t += 1024)
        buf[0][t] = make_float2(softplus_f(Hrow[t]), 0.0f);
    __syncthreads();

#pragma unroll
    for (int i = 0; i < 6; ++i) {
        const int   sh    = 2 * i;
        const int   st    = 1 << sh;                   // 4^i
        const float inv_n = 1.0f / (float)(MM >> sh);  // 1 / n_i
        const float2* cur = buf[i & 1];
        float2*       nxt = buf[(i & 1) ^ 1];

        const int t = tid;
        const int p = t >> sh;
        const int q = t & (st - 1);

        const float2 a0 = cur[t];
        const float2 a1 = cur[t + 1024];
        const float2 a2 = cur[t + 2048];
        const float2 a3 = cur[t + 3072];

        const float e0x = a0.x + a2.x, e0y = a0.y + a2.y;
        const float e1x = a1.x + a3.x, e1y = a1.y + a3.y;
        const float o0x = a0.x - a2.x, o0y = a0.y - a2.y;
        const float o1x = a1.x - a3.x, o1y = a1.y - a3.y;

        const float2 y0 = make_float2(e0x + e1x, e0y + e1y);
        const float2 y2 = make_float2(e0x - e1x, e0y - e1y);
        const float2 y1 = make_float2(o0x + o1y, o0y - o1x);   // o0 - i*o1
        const float2 y3 = make_float2(o0x - o1y, o0y + o1x);   // o0 + i*o1

        const float th = (float)p * inv_n;                     // [0, 0.25)
        const float c1 = __builtin_amdgcn_cosf(th);
        const float s1 = __builtin_amdgcn_sinf(th);
        const float c2 = fmaf(-2.0f * s1, s1, 1.0f);
        const float s2 = 2.0f * s1 * c1;
        const float c3 = c1 * c2 - s1 * s2;
        const float s3 = s1 * c2 + c1 * s2;

        const int base = 4 * t - 3 * q;        // q + st*4p
        nxt[base]          = y0;
        nxt[base + st]     = make_float2(fmaf(y1.x, c1,  y1.y * s1),
                                         fmaf(y1.y, c1, -y1.x * s1));
        nxt[base + 2*st]   = make_float2(fmaf(y2.x, c2,  y2.y * s2),
                                         fmaf(y2.y, c2, -y2.x * s2));
        nxt[base + 3*st]   = make_float2(fmaf(y3.x, c3,  y3.y * s3),
                                         fmaf(y3.y, c3, -y3.x * s3));
        __syncthreads();
    }

    for (int t = tid; t < MM; t += 1024)
        hft[(size_t)d * MM + t] = buf[0][t];
}

// ---------------------------------------------------------------------------
// Kernel B (real output, Hermitian-pair, LDS-staged, d-chunked):
//   z = A e^{-i 2pi tf m} Hft[d,m]  ->  Re V[n,m]      += Re z
//                                       Re V[n,4096-m] += Reu*Rez + Imu*Imz
// Block: 256 thr = 8 rows x 32 lanes; covers 8 n-rows x 128 m-cols (K=4).
// Hft staged to LDS in 4 chunks of 8 d-rows, double-buffered (16 KB) —
// removes the 8x cross-row redundant global reads of round 6.
// Grid (2048/128, 512/8) = (16, 64) = 1024 blocks -> 4 waves/SIMD.
// ---------------------------------------------------------------------------
__global__ __launch_bounds__(256) void shiftnmf_real(const float* __restrict__ W,
                                                     const float* __restrict__ tau,
                                                     const float2* __restrict__ hft,
                                                     float* __restrict__ out) {
    __shared__ float2 htile[2][8][128];   // 16 KB, double-buffered d-chunks
    __shared__ float  spw_s[8][RR];
    __shared__ float  tf_s[8][RR];
    __shared__ float  cu_s[8][RR];
    __shared__ float  su_s[8][RR];
    __shared__ float  h2048_s[RR];

    const int tid = threadIdx.x;
    const int mb  = blockIdx.x * 128;      // [0, 2048)
    const int nb  = blockIdx.y * 8;

    {   // per-row params: 256 threads cover 8 rows x 32 d
        const int nl = tid >> 5;
        const int dd = tid & 31;
        const float w = W[(size_t)(nb + nl) * RR + dd];
        const float t = tau[(size_t)(nb + nl) * RR + dd];
        spw_s[nl][dd] = softplus_f(w);
        tf_s[nl][dd]  = t * (1.0f / (float)MM);
        const float fr = t - floorf(t);                // frac(tau)
        cu_s[nl][dd] =  __builtin_amdgcn_cosf(fr);     // Re e^{-2pi i tau}
        su_s[nl][dd] = -__builtin_amdgcn_sinf(fr);     // Im e^{-2pi i tau}
    }
    if (tid < RR) h2048_s[tid] = hft[(size_t)tid * MM + 2048].x;

    // stage chunk 0 (d = 0..7) directly
    {
#pragma unroll
        for (int jj = 0; jj < 4; ++jj) {
            const int idx = tid + 256 * jj;          // 0..1023
            const int r   = idx >> 7;                // 0..7
            const int cl  = idx & 127;
            htile[0][r][cl] = hft[(size_t)r * MM + mb + cl];
        }
    }
    __syncthreads();

    const int g  = tid >> 5;        // row group 0..7
    const int ml = tid & 31;
    const int n  = nb + g;
    const float m0f = (float)(mb + ml);

    float accm[4], accp[4];
#pragma unroll
    for (int j = 0; j < 4; ++j) { accm[j] = 0.0f; accp[j] = 0.0f; }

    for (int c = 0; c < 4; ++c) {
        // issue next-chunk global loads early (hidden under compute)
        float2 nx0, nx1, nx2, nx3;
        if (c < 3) {
            const float2* src = hft + (size_t)(8 * (c + 1)) * MM + mb;
            const int i0 = tid, i1 = tid + 256, i2 = tid + 512, i3 = tid + 768;
            nx0 = src[(size_t)(i0 >> 7) * MM + (i0 & 127)];
            nx1 = src[(size_t)(i1 >> 7) * MM + (i1 & 127)];
            nx2 = src[(size_t)(i2 >> 7) * MM + (i2 & 127)];
            nx3 = src[(size_t)(i3 >> 7) * MM + (i3 & 127)];
        }

        const int cb_idx = c & 1;
#pragma unroll
        for (int dl = 0; dl < 8; ++dl) {
            const int d = 8 * c + dl;
            const float A  = spw_s[g][d];
            const float tf = tf_s[g][d];
            const float ru = cu_s[g][d];
            const float iu = su_s[g][d];

            float r0 = tf * m0f;   r0 -= floorf(r0);
            float dlr = tf * 32.0f; dlr -= floorf(dlr);
            const float c0 = __builtin_amdgcn_cosf(r0);
            const float s0 = __builtin_amdgcn_sinf(r0);
            const float cd = __builtin_amdgcn_cosf(dlr);
            const float sd = __builtin_amdgcn_sinf(dlr);
            float ca = A * c0, sa = A * s0;               // phasor, m = ml
            float cb = ca * cd - sa * sd;                 // phasor, m = ml+32
            float sb = sa * cd + ca * sd;
            const float c2 = fmaf(-2.0f * sd, sd, 1.0f);  // rotate by 2*delta
            const float s2 = 2.0f * sd * cd;

            const float2 h0 = htile[cb_idx][dl][ml];
            const float2 h1 = htile[cb_idx][dl][ml + 32];
            const float2 h2 = htile[cb_idx][dl][ml + 64];
            const float2 h3 = htile[cb_idx][dl][ml + 96];

            // j=0 (phasor a), j=1 (phasor b)
            {
                const float rz = fmaf(ca, h0.x,   sa * h0.y);
                const float iz = fmaf(ca, h0.y, -(sa * h0.x));
                accm[0] += rz;
                accp[0]  = fmaf(ru, rz, fmaf(iu, iz, accp[0]));
            }
            {
                const float rz = fmaf(cb, h1.x,   sb * h1.y);
                const float iz = fmaf(cb, h1.y, -(sb * h1.x));
                accm[1] += rz;
                accp[1]  = fmaf(ru, rz, fmaf(iu, iz, accp[1]));
            }
            // advance both phasors by 2*delta
            {
                const float can = fmaf(ca, c2, -(sa * s2));
                const float san = fmaf(sa, c2,  (ca * s2));
                const float cbn = fmaf(cb, c2, -(sb * s2));
                const float sbn = fmaf(sb, c2,  (cb * s2));
                ca = can; sa = san; cb = cbn; sb = sbn;
            }
            // j=2 (a), j=3 (b)
            {
                const float rz = fmaf(ca, h2.x,   sa * h2.y);
                const float iz = fmaf(ca, h2.y, -(sa * h2.x));
                accm[2] += rz;
                accp[2]  = fmaf(ru, rz, fmaf(iu, iz, accp[2]));
            }
            {
                const float rz = fmaf(cb, h3.x,   sb * h3.y);
                const float iz = fmaf(cb, h3.y, -(sb * h3.x));
                accm[3] += rz;
                accp[3]  = fmaf(ru, rz, fmaf(iu, iz, accp[3]));
            }
        }

        if (c < 3) {
            float2 (*dst)[128] = htile[(c + 1) & 1];
            const int i0 = tid, i1 = tid + 256, i2 = tid + 512, i3 = tid + 768;
            dst[i0 >> 7][i0 & 127] = nx0;
            dst[i1 >> 7][i1 & 127] = nx1;
            dst[i2 >> 7][i2 & 127] = nx2;
            dst[i3 >> 7][i3 & 127] = nx3;
        }
        __syncthreads();
    }

    float* orow = out + (size_t)n * MM;
#pragma unroll
    for (int j = 0; j < 4; ++j) {
        const int m = mb + ml + 32 * j;        // [0, 2047]
        orow[m] = accm[j];
        if (m != 0) orow[MM - m] = accp[j];    // [2049, 4095]
    }

    // Nyquist column m = 2048 (real bin): one lane per row, bx==0 blocks.
    if (blockIdx.x == 0 && ml == 0) {
        float acc = 0.0f;
        for (int d = 0; d < RR; ++d) {
            float r = tf_s[g][d] * 2048.0f;
            r -= floorf(r);
            acc = fmaf(spw_s[g][d] * h2048_s[d], __builtin_amdgcn_cosf(r), acc);
        }
        orow[2048] = acc;
    }
}

// ---------------------------------------------------------------------------
// Kernel B' (complex output hedge) — round-5 kernel, unchanged (proven).
// ---------------------------------------------------------------------------
__global__ __launch_bounds__(256) void shiftnmf_cplx(const float* __restrict__ W,
                                                     const float* __restrict__ tau,
                                                     const float2* __restrict__ hft,
                                                     float* __restrict__ out) {
    __shared__ float spw_s[16][RR];
    __shared__ float tau_s[16][RR];

    const int tid = threadIdx.x;
    const int mb  = blockIdx.x * 256;
    const int nb  = blockIdx.y * 16;

    for (int idx = tid; idx < 16 * RR; idx += 256) {
        const int nl = idx >> 5;
        const int dd = idx & 31;
        spw_s[nl][dd] = softplus_f(W[(size_t)(nb + nl) * RR + dd]);
        tau_s[nl][dd] = tau[(size_t)(nb + nl) * RR + dd] * (1.0f / (float)MM);
    }
    __syncthreads();

    const int g  = tid >> 5;
    const int ml = tid & 31;
    const int n0 = g * 2;
    const float m0f = (float)(mb + ml);
    const float2* hcol = hft + mb + ml;

    float accR[2][8], accI[2][8];
#pragma unroll
    for (int j = 0; j < 2; ++j)
#pragma unroll
        for (int k = 0; k < 8; ++k) { accR[j][k] = 0.0f; accI[j][k] = 0.0f; }

    float2 hc[8], hn[8];
#pragma unroll
    for (int k = 0; k < 8; ++k) hc[k] = hcol[32 * k];

    for (int d = 0; d < RR; ++d) {
        const float2* hnp = hcol + (size_t)((d + 1 < RR) ? d + 1 : d) * MM;
#pragma unroll
        for (int k = 0; k < 8; ++k) hn[k] = hnp[32 * k];

#pragma unroll
        for (int j = 0; j < 2; ++j) {
            const float A  = spw_s[n0 + j][d];
            const float tf = tau_s[n0 + j][d];
            float r0 = tf * m0f;  r0 -= floorf(r0);
            float dl = tf * 32.0f; dl -= floorf(dl);
            const float c0 = __builtin_amdgcn_cosf(r0);
            const float s0 = __builtin_amdgcn_sinf(r0);
            const float cd = __builtin_amdgcn_cosf(dl);
            const float sd = __builtin_amdgcn_sinf(dl);
            float ca = A * c0, sa = A * s0;
            float cb = ca * cd - sa * sd;
            float sb = sa * cd + ca * sd;
            const float c2 = fmaf(-2.0f * sd, sd, 1.0f);
            const float s2 = 2.0f * sd * cd;

#pragma unroll
            for (int t4 = 0; t4 < 4; ++t4) {
                const float2 h0 = hc[2 * t4];
                const float2 h1 = hc[2 * t4 + 1];
                accR[j][2*t4]   = fmaf(ca, h0.x, fmaf(sa, h0.y, accR[j][2*t4]));
                accR[j][2*t4+1] = fmaf(cb, h1.x, fmaf(sb, h1.y, accR[j][2*t4+1]));
                accI[j][2*t4]   = fmaf(ca, h0.y, fmaf(-sa, h0.x, accI[j][2*t4]));
                accI[j][2*t4+1] = fmaf(cb, h1.y, fmaf(-sb, h1.x, accI[j][2*t4+1]));
                if (t4 < 3) {
                    const float can = fmaf(ca, c2, -(sa * s2));
                    const float san = fmaf(sa, c2,  (ca * s2));
                    const float cbn = fmaf(cb, c2, -(sb * s2));
                    const float sbn = fmaf(sb, c2,  (cb * s2));
                    ca = can; sa = san; cb = cbn; sb = sbn;
                }
            }
        }
#pragma unroll
        for (int k = 0; k < 8; ++k) hc[k] = hn[k];
    }

#pragma unroll
    for (int j = 0; j < 2; ++j) {
        float2* orow = (float2*)out + (size_t)(nb + n0 + j) * MM + mb + ml;
#pragma unroll
        for (int k = 0; k < 8; ++k)
            orow[32 * k] = make_float2(accR[j][k], accI[j][k]);
    }
}

extern "C" void kernel_launch(void* const* d_in, const int* in_sizes, int n_in,
                              void* d_out, int out_size, void* d_ws, size_t ws_size,
                              hipStream_t stream) {
    const float* W   = (const float*)d_in[0];   // (512, 32)
    const float* H   = (const float*)d_in[1];   // (32, 4096)
    const float* tau = (const float*)d_in[2];   // (512, 32)

    const size_t hft_bytes = (size_t)RR * MM * sizeof(float2);  // 1 MB
    if (ws_size < hft_bytes) return;            // safe bail (no crash)
    float2* hft = (float2*)d_ws;

    fft_rows_kernel<<<RR, 1024, 0, stream>>>(H, hft);

    if (out_size >= 2 * NN * MM) {
        dim3 grid(MM / 256, NN / 16);
        shiftnmf_cplx<<<grid, 256, 0, stream>>>(W, tau, hft, (float*)d_out);
    } else {
        dim3 grid(2048 / 128, NN / 8);
        shiftnmf_real<<<grid, 256, 0, stream>>>(W, tau, hft, (float*)d_out);
    }
}

// Round 8
// 30.719 us; speedup vs baseline: 1.0456x; 1.0456x over previous
//
#include <hip/hip_runtime.h>
#include <hip/hip_bf16.h>

#define MM 4096
#define NN 512
#define RR 32

__device__ __forceinline__ float softplus_f(float x) {
    return x > 20.0f ? x : log1pf(__expf(x));
}

__device__ __forceinline__ int bitrev6(int l) {
    return ((l & 1) << 5) | ((l & 2) << 3) | ((l & 4) << 1) |
           ((l & 8) >> 1) | ((l & 16) >> 3) | ((l & 32) >> 5);
}

// In-register 64-point DIF FFT across the 64 lanes of a wave.
// Input: lane l holds x[l]. Output: lane l holds X[bitrev6(l)].
// Convention X[k] = sum_n x[n] e^{-2pi i nk/64}.
__device__ __forceinline__ void wave_fft64(float& xr, float& xi) {
#pragma unroll
    for (int s = 32; s >= 1; s >>= 1) {
        const float pr = __shfl_xor(xr, s, 64);
        const float pi = __shfl_xor(xi, s, 64);
        const int   lane = threadIdx.x & 63;
        const bool  hi = (lane & s) != 0;
        // lo lanes: u = x + p ; hi lanes: v = (p - x) * W_{2s}^{lane & (s-1)}
        const float ur = xr + pr, ui = xi + pi;
        const float vr = pr - xr, vi = pi - xi;
        const int   j  = lane & (s - 1);
        const float rev = (float)j * (1.0f / (float)(2 * s));   // [0, 0.5)
        const float ct = __builtin_amdgcn_cosf(rev);
        const float st = __builtin_amdgcn_sinf(rev);
        const float wr = fmaf(vr, ct,   vi * st);   // v * (ct - i st)
        const float wi = fmaf(vi, ct, -(vr * st));
        xr = hi ? wr : ur;
        xi = hi ? wi : ui;
    }
}

// ---------------------------------------------------------------------------
// FFT step 1: for each (d, n1): FFT-64 over n2 of softplus(H)[d][n1 + 64*n2],
// twiddle by W_4096^{n1*k2}, store z to scratch[d][k2][n1] (transposed).
// 2048 waves = 512 blocks x 256 thr -> whole GPU busy.
// ---------------------------------------------------------------------------
__global__ __launch_bounds__(256) void fft64_step1(const float* __restrict__ H,
                                                   float2* __restrict__ zbuf) {
    const int wave = (blockIdx.x * 256 + threadIdx.x) >> 6;   // 0..2047
    const int lane = threadIdx.x & 63;                        // n2
    const int d    = wave >> 6;                               // 0..31
    const int n1   = wave & 63;                               // 0..63

    float xr = softplus_f(H[(size_t)d * MM + n1 + 64 * lane]);
    float xi = 0.0f;
    wave_fft64(xr, xi);

    const int k2 = bitrev6(lane);
    // twiddle: z = X * e^{-2pi i n1 k2 / 4096}
    const float rev = (float)(n1 * k2) * (1.0f / 4096.0f);    // [0,1), exact
    const float ct = __builtin_amdgcn_cosf(rev);
    const float st = __builtin_amdgcn_sinf(rev);
    const float zr = fmaf(xr, ct,   xi * st);
    const float zi = fmaf(xi, ct, -(xr * st));

    zbuf[(size_t)d * MM + k2 * 64 + n1] = make_float2(zr, zi);
}

// ---------------------------------------------------------------------------
// FFT step 2: for each (d, k2): FFT-64 over n1 of z[d][k2][n1] (contiguous),
// scatter result to hft[d][k2 + 64*k1], k1 = bitrev6(lane).
// ---------------------------------------------------------------------------
__global__ __launch_bounds__(256) void fft64_step2(const float2* __restrict__ zbuf,
                                                   float2* __restrict__ hft) {
    const int wave = (blockIdx.x * 256 + threadIdx.x) >> 6;   // 0..2047
    const int lane = threadIdx.x & 63;                        // n1
    const int d    = wave >> 6;
    const int k2   = wave & 63;

    const float2 z = zbuf[(size_t)d * MM + k2 * 64 + lane];
    float xr = z.x, xi = z.y;
    wave_fft64(xr, xi);

    const int k1 = bitrev6(lane);
    hft[(size_t)d * MM + k2 + 64 * k1] = make_float2(xr, xi);
}

// ---------------------------------------------------------------------------
// Kernel B (real output, Hermitian-pair) — exact revert to round 6 (best
// measured). z = A e^{-i 2pi tf m} Hft[d,m]:
//   Re V[n,m] += Re z ;  Re V[n,4096-m] += Reu*Rez + Imu*Imz,
// u = e^{-2pi i tau}. Block: 8 rows x 32 lanes, K=8 m per thread.
// Grid (2048/256, 512/8) = (8, 64) = 512 blocks.
// ---------------------------------------------------------------------------
__global__ __launch_bounds__(256) void shiftnmf_real(const float* __restrict__ W,
                                                     const float* __restrict__ tau,
                                                     const float2* __restrict__ hft,
                                                     float* __restrict__ out) {
    __shared__ float spw_s[8][RR];
    __shared__ float tf_s[8][RR];
    __shared__ float cu_s[8][RR];
    __shared__ float su_s[8][RR];
    __shared__ float h2048_s[RR];

    const int tid = threadIdx.x;
    const int mb  = blockIdx.x * 256;      // [0, 2048)
    const int nb  = blockIdx.y * 8;

    {
        const int nl = tid >> 5;
        const int dd = tid & 31;
        const float w = W[(size_t)(nb + nl) * RR + dd];
        const float t = tau[(size_t)(nb + nl) * RR + dd];
        spw_s[nl][dd] = softplus_f(w);
        tf_s[nl][dd]  = t * (1.0f / (float)MM);
        const float fr = t - floorf(t);                // frac(tau)
        cu_s[nl][dd] =  __builtin_amdgcn_cosf(fr);     // Re e^{-2pi i tau}
        su_s[nl][dd] = -__builtin_amdgcn_sinf(fr);     // Im e^{-2pi i tau}
    }
    if (tid < RR) h2048_s[tid] = hft[(size_t)tid * MM + 2048].x;
    __syncthreads();

    const int g  = tid >> 5;
    const int ml = tid & 31;
    const int n  = nb + g;
    const float m0f = (float)(mb + ml);
    const float2* hcol = hft + mb + ml;

    float accm[8], accp[8];
#pragma unroll
    for (int k = 0; k < 8; ++k) { accm[k] = 0.0f; accp[k] = 0.0f; }

    float2 hc[8], hn[8];
#pragma unroll
    for (int k = 0; k < 8; ++k) hc[k] = hcol[32 * k];

    for (int d = 0; d < RR; ++d) {
        const float2* hnp = hcol + (size_t)((d + 1 < RR) ? d + 1 : d) * MM;
#pragma unroll
        for (int k = 0; k < 8; ++k) hn[k] = hnp[32 * k];

        const float A  = spw_s[g][d];
        const float tf = tf_s[g][d];
        const float ru = cu_s[g][d];
        const float iu = su_s[g][d];

        float r0 = tf * m0f;   r0 -= floorf(r0);
        float dl = tf * 32.0f; dl -= floorf(dl);
        const float c0 = __builtin_amdgcn_cosf(r0);
        const float s0 = __builtin_amdgcn_sinf(r0);
        const float cd = __builtin_amdgcn_cosf(dl);
        const float sd = __builtin_amdgcn_sinf(dl);
        float ca = A * c0, sa = A * s0;               // phasor for even k
        float cb = ca * cd - sa * sd;                 // phasor for odd k
        float sb = sa * cd + ca * sd;
        const float c2 = fmaf(-2.0f * sd, sd, 1.0f);  // rotate by 2*delta
        const float s2 = 2.0f * sd * cd;

#pragma unroll
        for (int t = 0; t < 4; ++t) {
            const float2 h0 = hc[2 * t];
            const float2 h1 = hc[2 * t + 1];
            {
                const float rz = fmaf(ca, h0.x,   sa * h0.y);
                const float iz = fmaf(ca, h0.y, -(sa * h0.x));
                accm[2 * t]     += rz;
                accp[2 * t]      = fmaf(ru, rz, fmaf(iu, iz, accp[2 * t]));
            }
            {
                const float rz = fmaf(cb, h1.x,   sb * h1.y);
                const float iz = fmaf(cb, h1.y, -(sb * h1.x));
                accm[2 * t + 1] += rz;
                accp[2 * t + 1]  = fmaf(ru, rz, fmaf(iu, iz, accp[2 * t + 1]));
            }
            if (t < 3) {
                const float can = fmaf(ca, c2, -(sa * s2));
                const float san = fmaf(sa, c2,  (ca * s2));
                const float cbn = fmaf(cb, c2, -(sb * s2));
                const float sbn = fmaf(sb, c2,  (cb * s2));
                ca = can; sa = san; cb = cbn; sb = sbn;
            }
        }
#pragma unroll
        for (int k = 0; k < 8; ++k) hc[k] = hn[k];
    }

    float* orow = out + (size_t)n * MM;
#pragma unroll
    for (int k = 0; k < 8; ++k) {
        const int m = mb + ml + 32 * k;       // [0, 2047]
        orow[m] = accm[k];
        if (m != 0) orow[MM - m] = accp[k];   // [2049, 4095]
    }

    // Nyquist column m = 2048 (real bin): one lane per row, bx==0 blocks.
    if (blockIdx.x == 0 && ml == 0) {
        float acc = 0.0f;
        for (int d = 0; d < RR; ++d) {
            float r = tf_s[g][d] * 2048.0f;
            r -= floorf(r);
            acc = fmaf(spw_s[g][d] * h2048_s[d], __builtin_amdgcn_cosf(r), acc);
        }
        orow[2048] = acc;
    }
}

// ---------------------------------------------------------------------------
// Kernel B' (complex output hedge) — round-5/6 kernel, unchanged.
// ---------------------------------------------------------------------------
__global__ __launch_bounds__(256) void shiftnmf_cplx(const float* __restrict__ W,
                                                     const float* __restrict__ tau,
                                                     const float2* __restrict__ hft,
                                                     float* __restrict__ out) {
    __shared__ float spw_s[16][RR];
    __shared__ float tau_s[16][RR];

    const int tid = threadIdx.x;
    const int mb  = blockIdx.x * 256;
    const int nb  = blockIdx.y * 16;

    for (int idx = tid; idx < 16 * RR; idx += 256) {
        const int nl = idx >> 5;
        const int dd = idx & 31;
        spw_s[nl][dd] = softplus_f(W[(size_t)(nb + nl) * RR + dd]);
        tau_s[nl][dd] = tau[(size_t)(nb + nl) * RR + dd] * (1.0f / (float)MM);
    }
    __syncthreads();

    const int g  = tid >> 5;
    const int ml = tid & 31;
    const int n0 = g * 2;
    const float m0f = (float)(mb + ml);
    const float2* hcol = hft + mb + ml;

    float accR[2][8], accI[2][8];
#pragma unroll
    for (int j = 0; j < 2; ++j)
#pragma unroll
        for (int k = 0; k < 8; ++k) { accR[j][k] = 0.0f; accI[j][k] = 0.0f; }

    float2 hc[8], hn[8];
#pragma unroll
    for (int k = 0; k < 8; ++k) hc[k] = hcol[32 * k];

    for (int d = 0; d < RR; ++d) {
        const float2* hnp = hcol + (size_t)((d + 1 < RR) ? d + 1 : d) * MM;
#pragma unroll
        for (int k = 0; k < 8; ++k) hn[k] = hnp[32 * k];

#pragma unroll
        for (int j = 0; j < 2; ++j) {
            const float A  = spw_s[n0 + j][d];
            const float tf = tau_s[n0 + j][d];
            float r0 = tf * m0f;  r0 -= floorf(r0);
            float dl = tf * 32.0f; dl -= floorf(dl);
            const float c0 = __builtin_amdgcn_cosf(r0);
            const float s0 = __builtin_amdgcn_sinf(r0);
            const float cd = __builtin_amdgcn_cosf(dl);
            const float sd = __builtin_amdgcn_sinf(dl);
            float ca = A * c0, sa = A * s0;
            float cb = ca * cd - sa * sd;
            float sb = sa * cd + ca * sd;
            const float c2 = fmaf(-2.0f * sd, sd, 1.0f);
            const float s2 = 2.0f * sd * cd;

#pragma unroll
            for (int t4 = 0; t4 < 4; ++t4) {
                const float2 h0 = hc[2 * t4];
                const float2 h1 = hc[2 * t4 + 1];
                accR[j][2*t4]   = fmaf(ca, h0.x, fmaf(sa, h0.y, accR[j][2*t4]));
                accR[j][2*t4+1] = fmaf(cb, h1.x, fmaf(sb, h1.y, accR[j][2*t4+1]));
                accI[j][2*t4]   = fmaf(ca, h0.y, fmaf(-sa, h0.x, accI[j][2*t4]));
                accI[j][2*t4+1] = fmaf(cb, h1.y, fmaf(-sb, h1.x, accI[j][2*t4+1]));
                if (t4 < 3) {
                    const float can = fmaf(ca, c2, -(sa * s2));
                    const float san = fmaf(sa, c2,  (ca * s2));
                    const float cbn = fmaf(cb, c2, -(sb * s2));
                    const float sbn = fmaf(sb, c2,  (cb * s2));
                    ca = can; sa = san; cb = cbn; sb = sbn;
                }
            }
        }
#pragma unroll
        for (int k = 0; k < 8; ++k) hc[k] = hn[k];
    }

#pragma unroll
    for (int j = 0; j < 2; ++j) {
        float2* orow = (float2*)out + (size_t)(nb + n0 + j) * MM + mb + ml;
#pragma unroll
        for (int k = 0; k < 8; ++k)
            orow[32 * k] = make_float2(accR[j][k], accI[j][k]);
    }
}

extern "C" void kernel_launch(void* const* d_in, const int* in_sizes, int n_in,
                              void* d_out, int out_size, void* d_ws, size_t ws_size,
                              hipStream_t stream) {
    const float* W   = (const float*)d_in[0];   // (512, 32)
    const float* H   = (const float*)d_in[1];   // (32, 4096)
    const float* tau = (const float*)d_in[2];   // (512, 32)

    const size_t hft_bytes = (size_t)RR * MM * sizeof(float2);  // 1 MB
    if (ws_size < 2 * hft_bytes) return;        // safe bail (no crash)
    float2* zbuf = (float2*)d_ws;               // step-1 intermediate (1 MB)
    float2* hft  = zbuf + (size_t)RR * MM;      // spectrum (1 MB)

    fft64_step1<<<512, 256, 0, stream>>>(H, zbuf);
    fft64_step2<<<512, 256, 0, stream>>>(zbuf, hft);

    if (out_size >= 2 * NN * MM) {
        dim3 grid(MM / 256, NN / 16);
        shiftnmf_cplx<<<grid, 256, 0, stream>>>(W, tau, hft, (float*)d_out);
    } else {
        dim3 grid(2048 / 256, NN / 8);
        shiftnmf_real<<<grid, 256, 0, stream>>>(W, tau, hft, (float*)d_out);
    }
}